// Round 7
// baseline (559.686 us; speedup 1.0000x reference)
//
#include <hip/hip_runtime.h>
#include <hip/hip_fp16.h>
#include <cstdint>
#include <cstddef>

#define N_NODES 100000
#define N_EDGES 1600000
#define BSHIFT 9
#define BSIZE (1 << BSHIFT)
#define NB ((N_NODES + BSIZE - 1) >> BSHIFT)   // 196 buckets
#define PTILE 4096

typedef _Float16 half8 __attribute__((ext_vector_type(8)));
typedef float floatx4 __attribute__((ext_vector_type(4)));

// ---------------------------------------------------------------------------
// edge_index dtype handling (int64 vs int32 delivered by JAX)
// ---------------------------------------------------------------------------
static __device__ __forceinline__ int edge_row(const void* ei, int i64, int e) {
    return i64 ? (int)((const long long*)ei)[e] : ((const int*)ei)[e];
}
static __device__ __forceinline__ int edge_col(const void* ei, int i64, int e) {
    return i64 ? (int)((const long long*)ei)[N_EDGES + e] : ((const int*)ei)[N_EDGES + e];
}

__global__ void detect_i64(const int* __restrict__ w, int* __restrict__ flag) {
    __shared__ int red[256];
    int acc = 0;
    for (int j = threadIdx.x; j < 2048; j += 256) {
        int k = j * 781;
        acc |= w[2 * k + 1];
    }
    red[threadIdx.x] = acc;
    __syncthreads();
    for (int off = 128; off > 0; off >>= 1) {
        if (threadIdx.x < off) red[threadIdx.x] |= red[threadIdx.x + off];
        __syncthreads();
    }
    if (threadIdx.x == 0) *flag = (red[0] == 0) ? 1 : 0;
}

// ---------------------------------------------------------------------------
// Preprocessing: no random global atomics anywhere.
// ---------------------------------------------------------------------------
__global__ void init_pre(int* __restrict__ bsize) {
    if (threadIdx.x < NB + 1) bsize[threadIdx.x] = 0;
}

__global__ void __launch_bounds__(256)
hist_buckets(const void* __restrict__ ei, const int* __restrict__ flag,
             int* __restrict__ bsize) {
    __shared__ int h[256];
    const int tid = threadIdx.x;
    const int tbase = blockIdx.x * PTILE;
    const int f = *flag;
    h[tid] = 0;
    __syncthreads();
    #pragma unroll
    for (int j = 0; j < PTILE / 256; ++j) {
        int idx = tbase + tid + j * 256;
        if (idx < N_EDGES) {
            int r = edge_row(ei, f, idx);
            atomicAdd(&h[r >> BSHIFT], 1);
        }
    }
    __syncthreads();
    if (tid < NB && h[tid] > 0) atomicAdd(&bsize[tid], h[tid]);
}

__global__ void scan_buckets(const int* __restrict__ bsize, int* __restrict__ bbase,
                             int* __restrict__ bcur) {
    __shared__ int sd[256];
    int t = threadIdx.x;
    int v = (t < NB) ? bsize[t] : 0;
    sd[t] = v;
    __syncthreads();
    for (int off = 1; off < 256; off <<= 1) {
        int add = (t >= off) ? sd[t - off] : 0;
        __syncthreads();
        sd[t] += add;
        __syncthreads();
    }
    if (t < NB) {
        bbase[t] = sd[t] - v;
        bcur[t] = sd[t] - v;
    }
    if (t == 255) bbase[NB] = sd[255];   // == N_EDGES
}

__global__ void __launch_bounds__(256)
partition_edges(const void* __restrict__ ei, const int* __restrict__ flag,
                int* __restrict__ bcur, int* __restrict__ bktRow,
                int* __restrict__ bktCol) {
    __shared__ int rows[PTILE];
    __shared__ int cols[PTILE];
    __shared__ int h[256], sc[256], exs[256], base_s[256], p[256];

    const int tid = threadIdx.x;
    const int tbase = blockIdx.x * PTILE;
    const int tot = min(PTILE, N_EDGES - tbase);
    const int f = *flag;

    h[tid] = 0;
    p[tid] = 0;
    __syncthreads();

    #pragma unroll
    for (int j = 0; j < PTILE / 256; ++j) {
        int idx = tbase + tid + j * 256;
        if (idx < N_EDGES) {
            int r = edge_row(ei, f, idx);
            atomicAdd(&h[r >> BSHIFT], 1);
        }
    }
    __syncthreads();

    sc[tid] = h[tid];
    __syncthreads();
    for (int off = 1; off < 256; off <<= 1) {
        int v = (tid >= off) ? sc[tid - off] : 0;
        __syncthreads();
        sc[tid] += v;
        __syncthreads();
    }
    exs[tid] = sc[tid] - h[tid];
    if (tid < NB && h[tid] > 0) base_s[tid] = atomicAdd(&bcur[tid], h[tid]);
    __syncthreads();

    #pragma unroll
    for (int j = 0; j < PTILE / 256; ++j) {
        int idx = tbase + tid + j * 256;
        if (idx < N_EDGES) {
            int r = edge_row(ei, f, idx);
            int c = edge_col(ei, f, idx);
            int b = r >> BSHIFT;
            int lp = atomicAdd(&p[b], 1);
            int slot = exs[b] + lp;
            rows[slot] = r;
            cols[slot] = c;
        }
    }
    __syncthreads();

    for (int slot = tid; slot < tot; slot += 256) {
        int r = rows[slot];
        int b = r >> BSHIFT;
        int addr = base_s[b] + (slot - exs[b]);
        bktRow[addr] = r;
        bktCol[addr] = cols[slot];
    }
}

__global__ void __launch_bounds__(512)
bucket_stats(const int* __restrict__ bktRow, const int* __restrict__ bbase,
             int* __restrict__ deg, int* __restrict__ rowst) {
    __shared__ int cnt[512];
    __shared__ int sd[512];
    const int b = blockIdx.x;
    const int t = threadIdx.x;
    const int start = bbase[b], end = bbase[b + 1];
    cnt[t] = 0;
    __syncthreads();
    for (int i = start + t; i < end; i += 512)
        atomicAdd(&cnt[bktRow[i] - (b << BSHIFT)], 1);
    __syncthreads();
    int v = cnt[t];
    sd[t] = v;
    __syncthreads();
    for (int off = 1; off < 512; off <<= 1) {
        int add = (t >= off) ? sd[t - off] : 0;
        __syncthreads();
        sd[t] += add;
        __syncthreads();
    }
    int node = (b << BSHIFT) + t;
    if (node < N_NODES) {
        deg[node] = v;
        rowst[node] = start + sd[t] - v;
    }
}

__global__ void compute_dis(const int* __restrict__ deg, float* __restrict__ dis) {
    int i = blockIdx.x * blockDim.x + threadIdx.x;
    if (i < N_NODES) dis[i] = rsqrtf((float)deg[i] + 1.0f);
}

__global__ void __launch_bounds__(512)
scatter_bucket(const int* __restrict__ bktRow, const int* __restrict__ bktCol,
               const int* __restrict__ bbase, const int* __restrict__ rowst,
               const float* __restrict__ dis, int2* __restrict__ csr_cn) {
    __shared__ int cur[512];
    __shared__ float dl[512];
    const int b = blockIdx.x;
    const int t = threadIdx.x;
    const int start = bbase[b], end = bbase[b + 1];
    int node = (b << BSHIFT) + t;
    cur[t] = (node < N_NODES) ? rowst[node] : 0;
    dl[t]  = (node < N_NODES) ? dis[node] : 0.f;
    __syncthreads();
    for (int i = start + t; i < end; i += 512) {
        int r = bktRow[i];
        int c = bktCol[i];
        int lr = r - (b << BSHIFT);
        int pos = atomicAdd(&cur[lr], 1);
        float nrm = dl[lr] * dis[c];
        csr_cn[pos] = make_int2(c, __float_as_int(nrm));
    }
}

// ---------------------------------------------------------------------------
// MFMA GEMM with XOR-swizzled LDS B tile (conflict-free b128 access).
// ---------------------------------------------------------------------------
template<typename TIn, int NT>
__global__ void __launch_bounds__(256)
gemm_mfma(const TIn* __restrict__ in, const float* __restrict__ W,
          __half* __restrict__ out, int Mfull) {
    constexpr int NCOL = NT * 16;
    __shared__ _Float16 Wt[NCOL * 128];

    const int tid = threadIdx.x;
    for (int chunkIdx = tid; chunkIdx < NCOL * 16; chunkIdx += 256) {
        int n = chunkIdx % NCOL;
        int c = chunkIdx / NCOL;
        half8 v;
        #pragma unroll
        for (int i = 0; i < 8; ++i) {
            int k = c * 8 + i;
            v[i] = (n < Mfull) ? (_Float16)W[k * Mfull + n] : (_Float16)0.f;
        }
        *(half8*)&Wt[n * 128 + (c ^ (n & 7)) * 8] = v;
    }
    __syncthreads();

    const int wave = tid >> 6, lane = tid & 63;
    const int quad = lane >> 4, m = lane & 15;
    const int rowbase = blockIdx.x * 64 + wave * 16;
    const int arow_i = rowbase + m;
    const bool avalid = arow_i < N_NODES;
    const TIn* arow = in + (size_t)(avalid ? arow_i : 0) * 128;

    half8 a[4];
    #pragma unroll
    for (int kt = 0; kt < 4; ++kt) {
        if constexpr (sizeof(TIn) == 4) {
            const float4* ptr = (const float4*)((const float*)arow + kt * 32 + quad * 8);
            float4 f0 = ptr[0];
            float4 f1 = ptr[1];
            a[kt][0] = (_Float16)f0.x; a[kt][1] = (_Float16)f0.y;
            a[kt][2] = (_Float16)f0.z; a[kt][3] = (_Float16)f0.w;
            a[kt][4] = (_Float16)f1.x; a[kt][5] = (_Float16)f1.y;
            a[kt][6] = (_Float16)f1.z; a[kt][7] = (_Float16)f1.w;
        } else {
            a[kt] = *(const half8*)((const _Float16*)arow + kt * 32 + quad * 8);
        }
    }

    floatx4 acc[NT];
    #pragma unroll
    for (int ct = 0; ct < NT; ++ct) acc[ct] = (floatx4){0.f, 0.f, 0.f, 0.f};

    #pragma unroll
    for (int ct = 0; ct < NT; ++ct) {
        #pragma unroll
        for (int kt = 0; kt < 4; ++kt) {
            int n = ct * 16 + m;
            half8 bfrag = *(const half8*)&Wt[n * 128 + ((kt * 4 + quad) ^ (m & 7)) * 8];
            acc[ct] = __builtin_amdgcn_mfma_f32_16x16x32_f16(a[kt], bfrag, acc[ct], 0, 0, 0);
        }
    }

    const int rs0 = rowbase + quad * 4;
    #pragma unroll
    for (int ct = 0; ct < NT; ++ct) {
        int col = ct * 16 + m;
        if (col >= Mfull) continue;
        #pragma unroll
        for (int r = 0; r < 4; ++r) {
            int rs = rs0 + r;
            if (rs < N_NODES)
                out[(size_t)rs * Mfull + col] = __float2half(acc[ct][r]);
        }
    }
}

// ---------------------------------------------------------------------------
// CSR aggregation, masked fixed-width groups of 8: every group (including the
// last partial one) issues 8 independent cn loads + 8 independent gathers;
// invalid slots clamp to e-1 (same cache line) with norm forced to 0.
// No serial per-edge tail. Next group's cn prefetched during current gathers.
// ---------------------------------------------------------------------------
#define GDEPTH 8

static __device__ __forceinline__ void load_cn_masked(const int2* __restrict__ cn,
                                                      int base, int e, int2* c) {
    #pragma unroll
    for (int q = 0; q < GDEPTH; ++q) {
        int idx = base + q;
        bool valid = idx < e;
        c[q] = cn[valid ? idx : (e - 1)];
        if (!valid) c[q].y = 0;   // nrm = 0.0f
    }
}

__global__ void agg_c128(const __half* __restrict__ t, const int* __restrict__ rowst,
                         const int* __restrict__ deg, const int2* __restrict__ cn,
                         const float* __restrict__ dis, const float* __restrict__ bias,
                         __half* __restrict__ out, int relu) {
    int w = blockIdx.x * (blockDim.x >> 6) + (threadIdx.x >> 6);
    int lane = threadIdx.x & 63;
    if (w >= N_NODES) return;
    int s = rowst[w], d = deg[w];
    float di = dis[w];
    float sn = di * di;
    float2 tv = __half22float2(((const __half2*)(t + (size_t)w * 128))[lane]);
    float2 bv = ((const float2*)bias)[lane];
    float ax = fmaf(sn, tv.x, bv.x);
    float ay = fmaf(sn, tv.y, bv.y);
    int e = s + d;
    if (s < e) {
        int2 c[GDEPTH];
        load_cn_masked(cn, s, e, c);
        int j = s;
        for (; j + GDEPTH < e; j += GDEPTH) {
            int2 n[GDEPTH];
            load_cn_masked(cn, j + GDEPTH, e, n);
            __half2 v[GDEPTH];
            #pragma unroll
            for (int q = 0; q < GDEPTH; ++q)
                v[q] = ((const __half2*)(t + (size_t)c[q].x * 128))[lane];
            #pragma unroll
            for (int q = 0; q < GDEPTH; ++q) {
                float2 fv = __half22float2(v[q]);
                float nw = __int_as_float(c[q].y);
                ax = fmaf(nw, fv.x, ax);
                ay = fmaf(nw, fv.y, ay);
            }
            #pragma unroll
            for (int q = 0; q < GDEPTH; ++q) c[q] = n[q];
        }
        __half2 v[GDEPTH];
        #pragma unroll
        for (int q = 0; q < GDEPTH; ++q)
            v[q] = ((const __half2*)(t + (size_t)c[q].x * 128))[lane];
        #pragma unroll
        for (int q = 0; q < GDEPTH; ++q) {
            float2 fv = __half22float2(v[q]);
            float nw = __int_as_float(c[q].y);
            ax = fmaf(nw, fv.x, ax);
            ay = fmaf(nw, fv.y, ay);
        }
    }
    if (relu) { ax = fmaxf(ax, 0.f); ay = fmaxf(ay, 0.f); }
    ((__half2*)(out + (size_t)w * 128))[lane] = __float22half2_rn(make_float2(ax, ay));
}

__global__ void agg_c47(const __half* __restrict__ t, const int* __restrict__ rowst,
                        const int* __restrict__ deg, const int2* __restrict__ cn,
                        const float* __restrict__ dis, const float* __restrict__ bias,
                        float* __restrict__ out) {
    int w = blockIdx.x * (blockDim.x >> 6) + (threadIdx.x >> 6);
    int lane = threadIdx.x & 63;
    if (w >= N_NODES) return;
    int s = rowst[w], d = deg[w];
    float di = dis[w];
    float sn = di * di;
    bool act = lane < 47;
    int li = act ? lane : 0;
    float acc = act ? fmaf(sn, (float)t[(size_t)w * 47 + li], bias[li]) : 0.f;
    int e = s + d;
    if (s < e) {
        int2 c[GDEPTH];
        load_cn_masked(cn, s, e, c);
        int j = s;
        for (; j + GDEPTH < e; j += GDEPTH) {
            int2 n[GDEPTH];
            load_cn_masked(cn, j + GDEPTH, e, n);
            __half v[GDEPTH];
            #pragma unroll
            for (int q = 0; q < GDEPTH; ++q)
                v[q] = t[(size_t)c[q].x * 47 + li];
            #pragma unroll
            for (int q = 0; q < GDEPTH; ++q)
                acc = fmaf(__int_as_float(c[q].y), (float)v[q], acc);
            #pragma unroll
            for (int q = 0; q < GDEPTH; ++q) c[q] = n[q];
        }
        __half v[GDEPTH];
        #pragma unroll
        for (int q = 0; q < GDEPTH; ++q)
            v[q] = t[(size_t)c[q].x * 47 + li];
        #pragma unroll
        for (int q = 0; q < GDEPTH; ++q)
            acc = fmaf(__int_as_float(c[q].y), (float)v[q], acc);
    }
    if (act) out[(size_t)w * 47 + lane] = acc;
}

// ---------------------------------------------------------------------------
extern "C" void kernel_launch(void* const* d_in, const int* in_sizes, int n_in,
                              void* d_out, int out_size, void* d_ws, size_t ws_size,
                              hipStream_t stream) {
    const float* x  = (const float*)d_in[0];
    const void*  ei = d_in[1];
    const float* W1 = (const float*)d_in[3];
    const float* b1 = (const float*)d_in[4];
    const float* W2 = (const float*)d_in[5];
    const float* b2 = (const float*)d_in[6];
    const float* W3 = (const float*)d_in[7];
    const float* b3 = (const float*)d_in[8];
    float* out = (float*)d_out;

    size_t off = 0;
    auto alloc = [&](size_t bytes) -> void* {
        void* p = (char*)d_ws + off;
        off += (bytes + 511) & ~(size_t)511;
        return p;
    };
    float*  dis     = (float*)alloc((size_t)N_NODES * 4);
    int*    deg     = (int*)  alloc((size_t)N_NODES * 4);
    int*    rowst   = (int*)  alloc((size_t)N_NODES * 4);
    int*    bsize   = (int*)  alloc((NB + 1) * 4);
    int*    bbase   = (int*)  alloc((NB + 1) * 4);
    int*    bcur    = (int*)  alloc(NB * 4);
    int*    flag    = (int*)  alloc(64);
    int2*   csr_cn  = (int2*) alloc((size_t)N_EDGES * 8);
    __half* tbuf    = (__half*)alloc((size_t)N_NODES * 128 * 2);
    __half* hbuf    = (__half*)alloc((size_t)N_NODES * 128 * 2);
    int*    bktRow  = (int*)hbuf;            // aliases hbuf during preprocessing
    int*    bktCol  = bktRow + N_EDGES;
    (void)ws_size; (void)in_sizes; (void)n_in; (void)out_size;

    int ptiles = (N_EDGES + PTILE - 1) / PTILE;   // 391

    detect_i64<<<1, 256, 0, stream>>>((const int*)ei, flag);
    init_pre<<<1, 256, 0, stream>>>(bsize);
    hist_buckets<<<ptiles, 256, 0, stream>>>(ei, flag, bsize);
    scan_buckets<<<1, 256, 0, stream>>>(bsize, bbase, bcur);
    partition_edges<<<ptiles, 256, 0, stream>>>(ei, flag, bcur, bktRow, bktCol);
    bucket_stats<<<NB, 512, 0, stream>>>(bktRow, bbase, deg, rowst);
    compute_dis<<<(N_NODES + 255) / 256, 256, 0, stream>>>(deg, dis);
    scatter_bucket<<<NB, 512, 0, stream>>>(bktRow, bktCol, bbase, rowst, dis, csr_cn);

    int gblocks = (N_NODES + 63) / 64;   // 1563

    gemm_mfma<float, 8><<<gblocks, 256, 0, stream>>>(x, W1, tbuf, 128);
    agg_c128<<<(N_NODES + 3) / 4, 256, 0, stream>>>(tbuf, rowst, deg, csr_cn, dis, b1, hbuf, 1);
    gemm_mfma<_Float16, 8><<<gblocks, 256, 0, stream>>>((_Float16*)hbuf, W2, tbuf, 128);
    agg_c128<<<(N_NODES + 3) / 4, 256, 0, stream>>>(tbuf, rowst, deg, csr_cn, dis, b2, hbuf, 1);
    gemm_mfma<_Float16, 3><<<gblocks, 256, 0, stream>>>((_Float16*)hbuf, W3, tbuf, 47);
    agg_c47<<<(N_NODES + 3) / 4, 256, 0, stream>>>(tbuf, rowst, deg, csr_cn, dis, b3, out);
}